// Round 2
// baseline (81.844 us; speedup 1.0000x reference)
//
#include <hip/hip_runtime.h>

#define BINS 10
#define TPB  256

// Pass 1: per-bin {count, sum-of-BCE} over valid elements.
// Register-resident accumulators (compare-select chain, no runtime indexing),
// single LDS block-reduce at the end, one atomicAdd per bin per block.
__global__ __launch_bounds__(TPB) void ghmc_hist_kernel(
    const float4* __restrict__ pred4,
    const int4*   __restrict__ tgt4,
    const int4*   __restrict__ lw4,
    float* __restrict__ g_sums,
    float* __restrict__ g_counts,
    int n4, int n)
{
    float acc_s[BINS];
    float acc_c[BINS];
    #pragma unroll
    for (int b = 0; b < BINS; ++b) { acc_s[b] = 0.f; acc_c[b] = 0.f; }

    auto proc = [&](float p, int t, int w) {
        // q = t ? -p : p  ==>  g = sigmoid(q), bce = softplus(q)
        float q   = __int_as_float(__float_as_int(p) ^ (int)((unsigned)t << 31));
        float aq  = fabsf(q);
        float e   = __expf(-aq);                    // exp(-|q|) in (0,1]
        float d   = 1.f + e;
        float r   = __builtin_amdgcn_rcpf(d);       // ~1ulp rcp
        float sig = (q >= 0.f) ? r : e * r;         // sigmoid(q) == g in [0,1]
        int bin   = (int)(sig * 10.f);
        bin = bin > (BINS - 1) ? (BINS - 1) : bin;
        bin = (w > 0) ? bin : 255;                  // invalid -> matches no bin
        // softplus(q) = max(q,0) + ln(1+exp(-|q|))
        float bce = fmaxf(q, 0.f) + __logf(d);
        #pragma unroll
        for (int b = 0; b < BINS; ++b) {
            bool m = (bin == b);
            acc_s[b] += m ? bce : 0.f;
            acc_c[b] += m ? 1.f : 0.f;
        }
    };

    const int stride = gridDim.x * TPB;
    const int tid = threadIdx.x;
    for (int i = blockIdx.x * TPB + tid; i < n4; i += stride) {
        float4 p = pred4[i];
        int4   t = tgt4[i];
        int4   w = lw4[i];
        proc(p.x, t.x, w.x);
        proc(p.y, t.y, w.y);
        proc(p.z, t.z, w.z);
        proc(p.w, t.w, w.w);
    }
    // scalar tail (N not divisible by 4)
    const float* predf = (const float*)pred4;
    const int*   tgtf  = (const int*)tgt4;
    const int*   lwf   = (const int*)lw4;
    for (int i = n4 * 4 + blockIdx.x * TPB + tid; i < n; i += stride) {
        proc(predf[i], tgtf[i], lwf[i]);
    }

    // Block reduce: one LDS write per accumulator, then tree.
    __shared__ float s_sum[BINS][TPB];
    __shared__ float s_cnt[BINS][TPB];
    #pragma unroll
    for (int b = 0; b < BINS; ++b) { s_sum[b][tid] = acc_s[b]; s_cnt[b][tid] = acc_c[b]; }
    __syncthreads();
    for (int s = TPB / 2; s > 0; s >>= 1) {
        if (tid < s) {
            #pragma unroll
            for (int b = 0; b < BINS; ++b) {
                s_sum[b][tid] += s_sum[b][tid + s];
                s_cnt[b][tid] += s_cnt[b][tid + s];
            }
        }
        __syncthreads();
    }
    if (tid < BINS) {
        atomicAdd(&g_sums[tid],   s_sum[tid][0]);
        atomicAdd(&g_counts[tid], s_cnt[tid][0]);
    }
}

// Pass 2: tiny finalize — reproduce the reference arithmetic order.
// Counts are exact (integers held in float, well below 2^24).
__global__ void ghmc_final_kernel(const float* __restrict__ g_sums,
                                  const float* __restrict__ g_counts,
                                  float* __restrict__ out)
{
    if (blockIdx.x == 0 && threadIdx.x == 0) {
        float ti = 0.f; int nb = 0;
        #pragma unroll
        for (int b = 0; b < BINS; ++b) {
            ti += g_counts[b];
            nb += (g_counts[b] > 0.f) ? 1 : 0;
        }
        float total = fmaxf(ti, 1.f);
        float n     = (float)(nb > 0 ? nb : 1);
        float loss  = 0.f;
        #pragma unroll
        for (int b = 0; b < BINS; ++b) {
            if (g_counts[b] > 0.f) {
                float w = (total / g_counts[b]) / n;   // w_bin[b]
                loss += w * g_sums[b];
            }
        }
        out[0] = loss / total * 1.0f;  // LOSS_WEIGHT = 1.0
    }
}

extern "C" void kernel_launch(void* const* d_in, const int* in_sizes, int n_in,
                              void* d_out, int out_size, void* d_ws, size_t ws_size,
                              hipStream_t stream)
{
    const float4* pred4 = (const float4*)d_in[0];
    const int4*   tgt4  = (const int4*)d_in[1];
    const int4*   lw4   = (const int4*)d_in[2];

    const int n  = in_sizes[0];
    const int n4 = n / 4;

    float* g_sums   = (float*)d_ws;
    float* g_counts = (float*)((char*)d_ws + BINS * sizeof(float));

    hipMemsetAsync(d_ws, 0, 2 * BINS * sizeof(float), stream);

    int blocks = (n4 + TPB - 1) / TPB;
    if (blocks > 2048) blocks = 2048;
    if (blocks < 1)    blocks = 1;

    ghmc_hist_kernel<<<blocks, TPB, 0, stream>>>(pred4, tgt4, lw4,
                                                 g_sums, g_counts, n4, n);
    ghmc_final_kernel<<<1, 64, 0, stream>>>(g_sums, g_counts, (float*)d_out);
}

// Round 3
// 58.413 us; speedup vs baseline: 1.4011x; 1.4011x over previous
//
#include <hip/hip_runtime.h>

#define BINS 10
#define TPB  256
#define NB_MAX 2048

// Pass 1: per-bin {count, sum-of-BCE} over valid elements.
// Register accumulators; counts packed in a u64 (6 bits/bin, drained every
// <=56 elements); LDS tree block-reduce; NO global atomics -- each block
// writes 20 partials to d_ws (layout part[bin][block], coalesced for pass 2).
__global__ __launch_bounds__(TPB) void ghmc_hist_kernel(
    const float4* __restrict__ pred4,
    const int4*   __restrict__ tgt4,
    const int4*   __restrict__ lw4,
    float* __restrict__ part_s,   // [BINS][nb]
    float* __restrict__ part_c,   // [BINS][nb]
    int n4, int n, int nb)
{
    float acc_s[BINS];
    float acc_c[BINS];
    #pragma unroll
    for (int b = 0; b < BINS; ++b) { acc_s[b] = 0.f; acc_c[b] = 0.f; }
    unsigned long long pack = 0ull;   // 10 x 6-bit counters
    int since = 0;                    // elements since last drain (<=56)

    auto drain = [&]() {
        #pragma unroll
        for (int b = 0; b < BINS; ++b)
            acc_c[b] += (float)((pack >> (6 * b)) & 63ull);
        pack = 0ull;
        since = 0;
    };

    auto proc = [&](float p, int t, int w) {
        // q = t ? -p : p  ==>  g = sigmoid(q), bce = softplus(q)
        float q   = __int_as_float(__float_as_int(p) ^ (int)((unsigned)t << 31));
        float aq  = fabsf(q);
        float e   = __expf(-aq);                  // exp(-|q|) in (0,1]
        float d   = 1.f + e;
        float r   = __builtin_amdgcn_rcpf(d);
        float sig = (q >= 0.f) ? r : e * r;       // sigmoid(q) == g in [0,1]
        int bin   = (int)(sig * 10.f);
        bin = bin > (BINS - 1) ? (BINS - 1) : bin;   // bin in [0,9]
        bool valid = (w > 0);
        float bce = fmaxf(q, 0.f) + __logf(d);    // softplus(q)
        int binm  = valid ? bin : 255;            // invalid matches no bin
        #pragma unroll
        for (int b = 0; b < BINS; ++b)
            acc_s[b] += (binm == b) ? bce : 0.f;
        pack += valid ? (1ull << (6 * bin)) : 0ull;
    };

    const int tid    = threadIdx.x;
    const int stride = gridDim.x * TPB;
    int i = blockIdx.x * TPB + tid;

    // 2x-unrolled grid-stride: 6 loads in flight per iteration
    for (; i + stride < n4; i += 2 * stride) {
        float4 pA = pred4[i];        float4 pB = pred4[i + stride];
        int4   tA = tgt4[i];         int4   tB = tgt4[i + stride];
        int4   wA = lw4[i];          int4   wB = lw4[i + stride];
        proc(pA.x, tA.x, wA.x); proc(pA.y, tA.y, wA.y);
        proc(pA.z, tA.z, wA.z); proc(pA.w, tA.w, wA.w);
        proc(pB.x, tB.x, wB.x); proc(pB.y, tB.y, wB.y);
        proc(pB.z, tB.z, wB.z); proc(pB.w, tB.w, wB.w);
        since += 8;
        if (since >= 56) drain();
    }
    for (; i < n4; i += stride) {
        float4 p = pred4[i]; int4 t = tgt4[i]; int4 w = lw4[i];
        proc(p.x, t.x, w.x); proc(p.y, t.y, w.y);
        proc(p.z, t.z, w.z); proc(p.w, t.w, w.w);
        since += 4;
        if (since >= 56) drain();
    }
    // scalar tail (N not divisible by 4)
    {
        const float* predf = (const float*)pred4;
        const int*   tgtf  = (const int*)tgt4;
        const int*   lwf   = (const int*)lw4;
        for (int j = n4 * 4 + blockIdx.x * TPB + tid; j < n; j += stride) {
            proc(predf[j], tgtf[j], lwf[j]);
            since += 1;
            if (since >= 56) drain();
        }
    }
    drain();

    // Block reduce via LDS tree.
    __shared__ float s_sum[BINS][TPB];
    __shared__ float s_cnt[BINS][TPB];
    #pragma unroll
    for (int b = 0; b < BINS; ++b) { s_sum[b][tid] = acc_s[b]; s_cnt[b][tid] = acc_c[b]; }
    __syncthreads();
    for (int s = TPB / 2; s > 0; s >>= 1) {
        if (tid < s) {
            #pragma unroll
            for (int b = 0; b < BINS; ++b) {
                s_sum[b][tid] += s_sum[b][tid + s];
                s_cnt[b][tid] += s_cnt[b][tid + s];
            }
        }
        __syncthreads();
    }
    if (tid < BINS) {
        part_s[tid * nb + blockIdx.x] = s_sum[tid][0];
        part_c[tid * nb + blockIdx.x] = s_cnt[tid][0];
    }
}

// Pass 2: reduce nb partials per bin (coalesced), compute the scalar loss.
__global__ __launch_bounds__(TPB) void ghmc_final_kernel(
    const float* __restrict__ part_s,
    const float* __restrict__ part_c,
    float* __restrict__ out, int nb)
{
    __shared__ float sh_s[BINS][4];
    __shared__ float sh_c[BINS][4];
    const int tid  = threadIdx.x;
    const int lane = tid & 63;
    const int wv   = tid >> 6;

    #pragma unroll
    for (int b = 0; b < BINS; ++b) {
        float s = 0.f, c = 0.f;
        for (int i = tid; i < nb; i += TPB) {
            s += part_s[b * nb + i];
            c += part_c[b * nb + i];
        }
        #pragma unroll
        for (int off = 32; off >= 1; off >>= 1) {
            s += __shfl_xor(s, off, 64);
            c += __shfl_xor(c, off, 64);
        }
        if (lane == 0) { sh_s[b][wv] = s; sh_c[b][wv] = c; }
    }
    __syncthreads();

    if (tid == 0) {
        float sums[BINS], cnts[BINS];
        float ti = 0.f; int nbins = 0;
        #pragma unroll
        for (int b = 0; b < BINS; ++b) {
            sums[b] = sh_s[b][0] + sh_s[b][1] + sh_s[b][2] + sh_s[b][3];
            cnts[b] = sh_c[b][0] + sh_c[b][1] + sh_c[b][2] + sh_c[b][3];
            ti += cnts[b];
            nbins += (cnts[b] > 0.f) ? 1 : 0;
        }
        float total = fmaxf(ti, 1.f);
        float nf    = (float)(nbins > 0 ? nbins : 1);
        float loss  = 0.f;
        #pragma unroll
        for (int b = 0; b < BINS; ++b) {
            if (cnts[b] > 0.f) {
                float w = (total / cnts[b]) / nf;   // w_bin[b]
                loss += w * sums[b];
            }
        }
        out[0] = loss / total * 1.0f;  // LOSS_WEIGHT = 1.0
    }
}

extern "C" void kernel_launch(void* const* d_in, const int* in_sizes, int n_in,
                              void* d_out, int out_size, void* d_ws, size_t ws_size,
                              hipStream_t stream)
{
    const float4* pred4 = (const float4*)d_in[0];
    const int4*   tgt4  = (const int4*)d_in[1];
    const int4*   lw4   = (const int4*)d_in[2];

    const int n  = in_sizes[0];
    const int n4 = n / 4;

    // grid size: cap at NB_MAX and at what d_ws can hold (2*BINS floats/block)
    int nb = (n4 + TPB - 1) / TPB;
    if (nb > NB_MAX) nb = NB_MAX;
    int ws_cap = (int)(ws_size / (2 * BINS * sizeof(float)));
    if (nb > ws_cap) nb = ws_cap;
    if (nb < 1) nb = 1;

    float* part_s = (float*)d_ws;
    float* part_c = part_s + (size_t)BINS * nb;

    ghmc_hist_kernel<<<nb, TPB, 0, stream>>>(pred4, tgt4, lw4,
                                             part_s, part_c, n4, n, nb);
    ghmc_final_kernel<<<1, TPB, 0, stream>>>(part_s, part_c, (float*)d_out, nb);
}